// Round 7
// baseline (51.115 us; speedup 1.0000x reference)
//
#include <hip/hip_runtime.h>

// UltralyticsDetect head, fused: per-level 1x1-conv GEMM (M=144, K=C, N=B*HW)
// in bf16 MFMA + in-register DFL softmax decode + output assembly.
// Output: (16, 8400, 84) f32.
//
// R7: 2 N-fragments per wave (128 anchors/block) -- each A-fragment ds_read
// feeds 2 MFMAs, halving the dominant LDS-read pipe per anchor (was 72
// ds_read_b128/chunk = ~864cyc vs 346cyc MFMA). BK=32 chunks keep the X
// prefetch at 16 VGPRs so total stays under the 128 cap (R4 spill lesson).
// Counted vmcnt(16) + raw s_barrier keeps X loads in flight across barriers.

typedef __bf16 bf16x8 __attribute__((ext_vector_type(8)));
typedef float  f32x4  __attribute__((ext_vector_type(4)));

#define NTHREADS 256

// W image in d_ws: per level, C/32 chunks of 144 rows * 64 B, pre-swizzled.
#define WCHUNK 9216              // 144 * 64 B
#define WOFF0 0
#define WOFF1 73728              // level0: 8 chunks
#define WOFF2 221184             // level1: 16 chunks ; level2: 16 chunks after

// round-half-up f32 -> bf16, pack two into one u32 (a -> low16, b -> high16)
__device__ __forceinline__ unsigned int pack_bf16(float a, float b) {
    unsigned int ua = __builtin_bit_cast(unsigned int, a);
    unsigned int ub = __builtin_bit_cast(unsigned int, b);
    return ((ua + 0x8000u) >> 16) | ((ub + 0x8000u) & 0xffff0000u);
}

// LDS tile: [144 rows][32 bf16] = 64B rows. Swizzle the 16B slot index by
// (row&3)^((row>>2)&1): the 16 lanes of a q4-group then cover all 8
// bank-quads twice -> 2-way conflict (free, m136).
__device__ __forceinline__ int swz32(int row, int kbyte) {
    return row * 64 + (kbyte ^ ((((row & 3) ^ ((row >> 2) & 1))) << 4));
}

// async global->LDS, 16B per lane; LDS dest must be wave-uniform base + lane*16
__device__ __forceinline__ void gload_lds16(const void* g, void* l) {
    __builtin_amdgcn_global_load_lds(
        (const __attribute__((address_space(1))) void*)g,
        (__attribute__((address_space(3))) void*)l, 16, 0, 0);
}

// ---------------- prep kernel: W f32 -> bf16, pre-swizzled into d_ws --------
__global__ __launch_bounds__(256)
void prep_w_kernel(const float* __restrict__ wb0, const float* __restrict__ wc0,
                   const float* __restrict__ wb1, const float* __restrict__ wc1,
                   const float* __restrict__ wb2, const float* __restrict__ wc2,
                   unsigned char* __restrict__ ws) {
    int uid = blockIdx.x * 256 + threadIdx.x;   // one unit = 8 k-elems
    if (uid >= 23040) return;                   // 4608 + 9216 + 9216
    const float* wb; const float* wc; int C; size_t off; int uu;
    if (uid < 4608)       { wb = wb0; wc = wc0; C = 256; off = WOFF0; uu = uid; }
    else if (uid < 13824) { wb = wb1; wc = wc1; C = 512; off = WOFF1; uu = uid - 4608; }
    else                  { wb = wb2; wc = wc2; C = 512; off = WOFF2; uu = uid - 13824; }
    const int kunits = C / 8;
    const int row = uu / kunits;
    const int k   = (uu % kunits) * 8;
    const float* src = ((row < 64) ? (wb + row * C) : (wc + (row - 64) * C)) + k;
    const float4 f0 = *(const float4*)(src);
    const float4 f1 = *(const float4*)(src + 4);
    uint4 p;
    p.x = pack_bf16(f0.x, f0.y);
    p.y = pack_bf16(f0.z, f0.w);
    p.z = pack_bf16(f1.x, f1.y);
    p.w = pack_bf16(f1.z, f1.w);
    const int chunk = k >> 5;            // 32-k chunks
    const int kg    = (k & 31) >> 3;     // 16B slot within row
    *(uint4*)(ws + off + (size_t)chunk * WCHUNK + swz32(row, kg * 16)) = p;
}

// ---------------- main kernel ----------------------------------------------
template <int LVL>
__device__ __forceinline__ void run_level(
        int rb,
        const float* __restrict__ x,
        const unsigned char* __restrict__ wimg_all,
        const float* __restrict__ bbox, const float* __restrict__ bcls,
        float* __restrict__ out,
        unsigned char* s_w) {

    constexpr int    C      = (LVL == 0) ? 256 : 512;
    constexpr int    GW     = (LVL == 0) ? 80 : (LVL == 1 ? 40 : 20);
    constexpr int    HW     = GW * GW;
    constexpr int    AOFF   = (LVL == 0) ? 0 : (LVL == 1 ? 6400 : 8000);
    constexpr float  STRIDE = (LVL == 0) ? 8.0f : (LVL == 1 ? 16.0f : 32.0f);
    constexpr int    TPB    = (HW + 127) / 128;  // 128-anchor tiles per image
    constexpr size_t WOFF   = (LVL == 0) ? WOFF0 : (LVL == 1 ? WOFF1 : WOFF2);
    const int nkc = C / 32;

    const int b    = rb / TPB;
    const int tile = rb % TPB;
    const int hw0  = tile * 128;
    const int nv   = (HW - hw0 < 128) ? (HW - hw0) : 128;  // valid anchors

    const int tid  = threadIdx.x;
    const int wv   = tid >> 6;        // wave 0..3
    const int lane = tid & 63;
    const int col  = lane & 15;       // MFMA n/col lane
    const int q4   = lane >> 4;       // MFMA row-quarter

    const float* xb = x + (size_t)b * C * HW;
    const unsigned char* wimg = wimg_all + WOFF;

    // this lane's two anchors (clamped for tail tiles)
    const int a0 = wv * 16 + col;
    const int a1 = 64 + a0;
    const int a0c = (a0 < nv) ? a0 : (nv - 1);
    const int a1c = (a1 < nv) ? a1 : (nv - 1);
    const float* xanc0 = xb + hw0 + a0c;
    const float* xanc1 = xb + hw0 + a1c;

    f32x4 acc[9][2];
#pragma unroll
    for (int m = 0; m < 9; ++m) {
        acc[m][0] = (f32x4){0.f, 0.f, 0.f, 0.f};
        acc[m][1] = (f32x4){0.f, 0.f, 0.f, 0.f};
    }

    float P[16];   // X prefetch: 8 k-values x 2 anchors (static-indexed only)

    // chunk CC covers k = CC*32 .. CC*32+31 ; this lane needs k = CC*32+q4*8+j
#define XLOAD(CC)                                                           \
    {                                                                       \
        const size_t _kb = (size_t)((CC) * 32 + q4 * 8) * HW;               \
        const float* _p0 = xanc0 + _kb;                                     \
        const float* _p1 = xanc1 + _kb;                                     \
        _Pragma("unroll")                                                   \
        for (int _j = 0; _j < 8; ++_j) {                                    \
            P[_j]     = _p0[(size_t)_j * HW];                               \
            P[8 + _j] = _p1[(size_t)_j * HW];                               \
        }                                                                   \
    }

#define WDMA(CC, BUF)                                                       \
    {                                                                       \
        _Pragma("unroll")                                                   \
        for (int _i = 0; _i < 3; ++_i) {                                    \
            int _u = tid + _i * 256;                                        \
            if (_u < 576)                                                   \
                gload_lds16(wimg + (size_t)(CC) * WCHUNK + _u * 16,         \
                            s_w + (BUF) * WCHUNK + _u * 16);                \
        }                                                                   \
    }

#define CVT(O, DST)                                                         \
    {                                                                       \
        uint4 _q;                                                           \
        _q.x = pack_bf16(P[(O) + 0], P[(O) + 1]);                           \
        _q.y = pack_bf16(P[(O) + 2], P[(O) + 3]);                           \
        _q.z = pack_bf16(P[(O) + 4], P[(O) + 5]);                           \
        _q.w = pack_bf16(P[(O) + 6], P[(O) + 7]);                           \
        DST = __builtin_bit_cast(bf16x8, _q);                               \
    }

    // ---- prologue: W chunk 0 DMA + X chunk 0 into regs ----
    WDMA(0, 0);
    XLOAD(0);
    __builtin_amdgcn_sched_barrier(0);
    asm volatile("s_waitcnt vmcnt(16)" ::: "memory");  // drain W(0), keep X(0)
    __builtin_amdgcn_s_barrier();
    __builtin_amdgcn_sched_barrier(0);

    for (int kc = 0; kc < nkc; ++kc) {
        const unsigned char* wb = s_w + (kc & 1) * WCHUNK;
        const bool more = (kc + 1 < nkc);

        if (more) WDMA(kc + 1, (kc & 1) ^ 1);   // start next W DMA first

        // convert this chunk's X (in flight since last iter; compiler waits)
        bf16x8 fA, fB;
        CVT(0, fA);
        CVT(8, fB);

        if (more) XLOAD(kc + 1);                // refill P for next chunk
        __builtin_amdgcn_sched_barrier(0);

        // MFMA: 9 M-tiles x 2 N-frags; one A-read feeds 2 MFMAs
#pragma unroll
        for (int m = 0; m < 9; ++m) {
            const bf16x8 af = *(const bf16x8*)(wb + swz32(m * 16 + col, q4 * 16));
            acc[m][0] = __builtin_amdgcn_mfma_f32_16x16x32_bf16(af, fA, acc[m][0], 0, 0, 0);
            acc[m][1] = __builtin_amdgcn_mfma_f32_16x16x32_bf16(af, fB, acc[m][1], 0, 0, 0);
        }
        __builtin_amdgcn_sched_barrier(0);

        if (more) asm volatile("s_waitcnt vmcnt(16)" ::: "memory");  // W only
        else      asm volatile("s_waitcnt vmcnt(0)"  ::: "memory");
        __builtin_amdgcn_s_barrier();
        __builtin_amdgcn_sched_barrier(0);
    }

#undef CVT
#undef WDMA
#undef XLOAD

    // ---- epilogue: in-register DFL decode + store ----
    // D layout (m89): value[r] = D[mtile*16 + q4*4 + r][col]
    float4 bcv[5];
#pragma unroll
    for (int m = 0; m < 5; ++m)
        bcv[m] = *(const float4*)(bcls + m * 16 + q4 * 4);

    const float LOG2E = 1.44269504088896f;

#pragma unroll
    for (int nf = 0; nf < 2; ++nf) {
        const int alocal = nf * 64 + wv * 16 + col;
        const bool valid = alocal < nv;
        const int hw = hw0 + alocal;

        float dist[4];
#pragma unroll
        for (int g = 0; g < 4; ++g) {
            const float4 bbv = *(const float4*)(bbox + g * 16 + q4 * 4);
            const float v0 = acc[g][nf][0] + bbv.x;
            const float v1 = acc[g][nf][1] + bbv.y;
            const float v2 = acc[g][nf][2] + bbv.z;
            const float v3 = acc[g][nf][3] + bbv.w;
            // softmax over 16 bins: 4 regs x 4 lanes (col, col+16, col+32, col+48)
            float mx = fmaxf(fmaxf(v0, v1), fmaxf(v2, v3));
            mx = fmaxf(mx, __shfl_xor(mx, 16));
            mx = fmaxf(mx, __shfl_xor(mx, 32));
            const float e0 = __builtin_amdgcn_exp2f((v0 - mx) * LOG2E);
            const float e1 = __builtin_amdgcn_exp2f((v1 - mx) * LOG2E);
            const float e2 = __builtin_amdgcn_exp2f((v2 - mx) * LOG2E);
            const float e3 = __builtin_amdgcn_exp2f((v3 - mx) * LOG2E);
            float s  = e0 + e1 + e2 + e3;
            float ws = e1 + 2.f * e2 + 3.f * e3 + (float)(q4 * 4) * s;
            s  += __shfl_xor(s, 16);
            s  += __shfl_xor(s, 32);
            ws += __shfl_xor(ws, 16);
            ws += __shfl_xor(ws, 32);
            dist[g] = ws / s;
        }

        if (valid) {
            const size_t obase = ((size_t)b * 8400 + AOFF + hw) * 84;
            if (q4 == 0) {
                const float ax = (float)(hw % GW) + 0.5f;
                const float ay = (float)(hw / GW) + 0.5f;
                f32x4 bx;
                bx[0] = (ax + 0.5f * (dist[2] - dist[0])) * STRIDE;
                bx[1] = (ay + 0.5f * (dist[3] - dist[1])) * STRIDE;
                bx[2] = (dist[0] + dist[2]) * STRIDE;
                bx[3] = (dist[1] + dist[3]) * STRIDE;
                *(f32x4*)(out + obase) = bx;
            }
#pragma unroll
            for (int m = 0; m < 5; ++m) {
                f32x4 v;
                v[0] = acc[m + 4][nf][0] + bcv[m].x;
                v[1] = acc[m + 4][nf][1] + bcv[m].y;
                v[2] = acc[m + 4][nf][2] + bcv[m].z;
                v[3] = acc[m + 4][nf][3] + bcv[m].w;
                *(f32x4*)(out + obase + 4 + m * 16 + q4 * 4) = v;
            }
        }
    }
}

__global__ __launch_bounds__(NTHREADS, 4)
void UltralyticsDetect_kernel(
        const float* __restrict__ x0, const float* __restrict__ x1, const float* __restrict__ x2,
        const unsigned char* __restrict__ wimg,
        const float* __restrict__ bb0, const float* __restrict__ bc0,
        const float* __restrict__ bb1, const float* __restrict__ bc1,
        const float* __restrict__ bb2, const float* __restrict__ bc2,
        float* __restrict__ out) {

    __shared__ __align__(16) unsigned char s_w[2 * WCHUNK];  // 18 KiB dbuf

    const int bid = blockIdx.x;
    // Long (K=512) levels first so the tail is filled by short level-0 blocks:
    // level 1: 16 b * 13 tiles = 208 ; level 2: 16*4 = 64 ; level 0: 16*50 = 800
    if (bid < 208) {
        run_level<1>(bid, x1, wimg, bb1, bc1, out, s_w);
    } else if (bid < 272) {
        run_level<2>(bid - 208, x2, wimg, bb2, bc2, out, s_w);
    } else {
        run_level<0>(bid - 272, x0, wimg, bb0, bc0, out, s_w);
    }
}

extern "C" void kernel_launch(void* const* d_in, const int* in_sizes, int n_in,
                              void* d_out, int out_size, void* d_ws, size_t ws_size,
                              hipStream_t stream) {
    const float* x0  = (const float*)d_in[0];
    const float* x1  = (const float*)d_in[1];
    const float* x2  = (const float*)d_in[2];
    const float* wb0 = (const float*)d_in[3];
    const float* bb0 = (const float*)d_in[4];
    const float* wc0 = (const float*)d_in[5];
    const float* bc0 = (const float*)d_in[6];
    const float* wb1 = (const float*)d_in[7];
    const float* bb1 = (const float*)d_in[8];
    const float* wc1 = (const float*)d_in[9];
    const float* bc1 = (const float*)d_in[10];
    const float* wb2 = (const float*)d_in[11];
    const float* bb2 = (const float*)d_in[12];
    const float* wc2 = (const float*)d_in[13];
    const float* bc2 = (const float*)d_in[14];

    unsigned char* wimg = (unsigned char*)d_ws;

    prep_w_kernel<<<90, 256, 0, stream>>>(wb0, wc0, wb1, wc1, wb2, wc2, wimg);

    UltralyticsDetect_kernel<<<1072, NTHREADS, 0, stream>>>(
        x0, x1, x2, wimg,
        bb0, bc0, bb1, bc1, bb2, bc2,
        (float*)d_out);
}

// Round 8
// 49.957 us; speedup vs baseline: 1.0232x; 1.0232x over previous
//
#include <hip/hip_runtime.h>

// UltralyticsDetect head, fused: per-level 1x1-conv GEMM (M=144, K=C, N=B*HW)
// in bf16 MFMA + in-register DFL softmax decode + output assembly.
// Output: (16, 8400, 84) f32.
//
// R8: BARRIER-FREE wave-private pipelines. Block = 1 wave (64 threads) owning
// 64 anchors (4 N-frags -> one A ds_read feeds 4 MFMAs). Each wave stages its
// own W chunk (pre-swizzled bf16 from prep kernel) into a private 2x9KB LDS
// dbuf via global_load_lds and self-paces with counted vmcnt(32) -- there is
// NO s_barrier anywhere, so a wave only waits on its own loads. 8 blocks/CU.
// X reads are 256B-contiguous per (q4,j) across the 4 frags; X addressing is
// SGPR-base + per-frag VGPR offset (zero VALU per load).

typedef __bf16 bf16x8 __attribute__((ext_vector_type(8)));
typedef float  f32x4  __attribute__((ext_vector_type(4)));

// W image in d_ws: per level, C/32 chunks of 144 rows * 64 B, pre-swizzled.
#define WCHUNK 9216              // 144 * 64 B
#define WOFF0 0
#define WOFF1 73728              // level0: 8 chunks
#define WOFF2 221184             // level1: 16 chunks ; level2: 16 chunks after

// round-half-up f32 -> bf16, pack two into one u32 (a -> low16, b -> high16)
__device__ __forceinline__ unsigned int pack_bf16(float a, float b) {
    unsigned int ua = __builtin_bit_cast(unsigned int, a);
    unsigned int ub = __builtin_bit_cast(unsigned int, b);
    return ((ua + 0x8000u) >> 16) | ((ub + 0x8000u) & 0xffff0000u);
}

// LDS tile: [144 rows][32 bf16] = 64B rows, 16B-slot swizzle.
__device__ __forceinline__ int swz32(int row, int kbyte) {
    return row * 64 + (kbyte ^ ((((row & 3) ^ ((row >> 2) & 1))) << 4));
}

// async global->LDS, 16B per lane; LDS dest must be wave-uniform base + lane*16
__device__ __forceinline__ void gload_lds16(const void* g, void* l) {
    __builtin_amdgcn_global_load_lds(
        (const __attribute__((address_space(1))) void*)g,
        (__attribute__((address_space(3))) void*)l, 16, 0, 0);
}

// ---------------- prep kernel: W f32 -> bf16, pre-swizzled into d_ws --------
__global__ __launch_bounds__(256)
void prep_w_kernel(const float* __restrict__ wb0, const float* __restrict__ wc0,
                   const float* __restrict__ wb1, const float* __restrict__ wc1,
                   const float* __restrict__ wb2, const float* __restrict__ wc2,
                   unsigned char* __restrict__ ws) {
    int uid = blockIdx.x * 256 + threadIdx.x;   // one unit = 8 k-elems
    if (uid >= 23040) return;                   // 4608 + 9216 + 9216
    const float* wb; const float* wc; int C; size_t off; int uu;
    if (uid < 4608)       { wb = wb0; wc = wc0; C = 256; off = WOFF0; uu = uid; }
    else if (uid < 13824) { wb = wb1; wc = wc1; C = 512; off = WOFF1; uu = uid - 4608; }
    else                  { wb = wb2; wc = wc2; C = 512; off = WOFF2; uu = uid - 13824; }
    const int kunits = C / 8;
    const int row = uu / kunits;
    const int k   = (uu % kunits) * 8;
    const float* src = ((row < 64) ? (wb + row * C) : (wc + (row - 64) * C)) + k;
    const float4 f0 = *(const float4*)(src);
    const float4 f1 = *(const float4*)(src + 4);
    uint4 p;
    p.x = pack_bf16(f0.x, f0.y);
    p.y = pack_bf16(f0.z, f0.w);
    p.z = pack_bf16(f1.x, f1.y);
    p.w = pack_bf16(f1.z, f1.w);
    const int chunk = k >> 5;            // 32-k chunks
    const int kg    = (k & 31) >> 3;     // 16B slot within row
    *(uint4*)(ws + off + (size_t)chunk * WCHUNK + swz32(row, kg * 16)) = p;
}

// ---------------- main kernel ----------------------------------------------
template <int LVL>
__device__ __forceinline__ void run_level(
        int rb,
        const float* __restrict__ x,
        const unsigned char* __restrict__ wimg_all,
        const float* __restrict__ bbox, const float* __restrict__ bcls,
        float* __restrict__ out,
        unsigned char* s_w) {

    constexpr int    C      = (LVL == 0) ? 256 : 512;
    constexpr int    GW     = (LVL == 0) ? 80 : (LVL == 1 ? 40 : 20);
    constexpr int    HW     = GW * GW;
    constexpr int    AOFF   = (LVL == 0) ? 0 : (LVL == 1 ? 6400 : 8000);
    constexpr float  STRIDE = (LVL == 0) ? 8.0f : (LVL == 1 ? 16.0f : 32.0f);
    constexpr int    TPB    = (HW + 63) / 64;   // 64-anchor tiles per image
    constexpr size_t WOFF   = (LVL == 0) ? WOFF0 : (LVL == 1 ? WOFF1 : WOFF2);
    const int nkc = C / 32;

    const int b    = rb / TPB;
    const int tile = rb % TPB;
    const int hw0  = tile * 64;
    const int nv   = (HW - hw0 < 64) ? (HW - hw0) : 64;  // valid anchors

    const int lane = threadIdx.x;     // 0..63, one wave
    const int col  = lane & 15;       // MFMA n/col lane
    const int q4   = lane >> 4;       // MFMA row-quarter

    const float* xhw = x + (size_t)b * C * HW + hw0;  // uniform base
    const unsigned char* wimg = wimg_all + WOFF;

    // per-frag anchor offsets (clamped for tail tiles)
    int af[4];
#pragma unroll
    for (int f = 0; f < 4; ++f) {
        const int a = f * 16 + col;
        af[f] = (a < nv) ? a : (nv - 1);
    }
    const int q4ofs = q4 * 8 * HW;   // lane-variant part of the k offset

    f32x4 acc[9][4];
#pragma unroll
    for (int m = 0; m < 9; ++m)
#pragma unroll
        for (int f = 0; f < 4; ++f)
            acc[m][f] = (f32x4){0.f, 0.f, 0.f, 0.f};

    float P[32];   // X prefetch: 4 frags x 8 k (static-indexed only)

    // chunk CC: lane needs X[k = CC*32 + q4*8 + j][anchor af[f]]
#define XLOAD(CC)                                                           \
    {                                                                       \
        const float* _pb = xhw + (size_t)(CC) * 32 * HW;                    \
        _Pragma("unroll")                                                   \
        for (int _j = 0; _j < 8; ++_j) {                                    \
            const float* _p = _pb + (size_t)_j * HW + q4ofs;                \
            _Pragma("unroll")                                               \
            for (int _f = 0; _f < 4; ++_f)                                  \
                P[_f * 8 + _j] = _p[af[_f]];                                \
        }                                                                   \
    }

#define WDMA(CC, BUF)                                                       \
    {                                                                       \
        _Pragma("unroll")                                                   \
        for (int _i = 0; _i < 9; ++_i) {                                    \
            const int _u = lane + _i * 64;                                  \
            gload_lds16(wimg + (size_t)(CC) * WCHUNK + _u * 16,             \
                        s_w + (BUF) * WCHUNK + _u * 16);                    \
        }                                                                   \
    }

#define CVT(O, DST)                                                         \
    {                                                                       \
        uint4 _q;                                                           \
        _q.x = pack_bf16(P[(O) + 0], P[(O) + 1]);                           \
        _q.y = pack_bf16(P[(O) + 2], P[(O) + 3]);                           \
        _q.z = pack_bf16(P[(O) + 4], P[(O) + 5]);                           \
        _q.w = pack_bf16(P[(O) + 6], P[(O) + 7]);                           \
        DST = __builtin_bit_cast(bf16x8, _q);                               \
    }

    // ---- prologue: W chunk 0 DMA + X chunk 0 into regs ----
    WDMA(0, 0);
    XLOAD(0);
    __builtin_amdgcn_sched_barrier(0);
    asm volatile("s_waitcnt vmcnt(32)" ::: "memory");  // drain W(0); X(0) flies
    __builtin_amdgcn_sched_barrier(0);

    for (int kc = 0; kc < nkc; ++kc) {
        const unsigned char* wb = s_w + (kc & 1) * WCHUNK;
        const bool more = (kc + 1 < nkc);

        if (more) WDMA(kc + 1, (kc & 1) ^ 1);   // issue next W DMA first
        __builtin_amdgcn_sched_barrier(0);

        // convert this chunk's X (auto vmcnt wait leaves the 9 W DMAs flying)
        bf16x8 f0, f1, f2, f3;
        CVT(0, f0);
        CVT(8, f1);
        CVT(16, f2);
        CVT(24, f3);

        if (more) XLOAD(kc + 1);                // refill P for next chunk
        __builtin_amdgcn_sched_barrier(0);

        // MFMA: 9 M-tiles x 4 N-frags; one A-read feeds 4 MFMAs
#pragma unroll
        for (int m = 0; m < 9; ++m) {
            const bf16x8 a_ = *(const bf16x8*)(wb + swz32(m * 16 + col, q4 * 16));
            acc[m][0] = __builtin_amdgcn_mfma_f32_16x16x32_bf16(a_, f0, acc[m][0], 0, 0, 0);
            acc[m][1] = __builtin_amdgcn_mfma_f32_16x16x32_bf16(a_, f1, acc[m][1], 0, 0, 0);
            acc[m][2] = __builtin_amdgcn_mfma_f32_16x16x32_bf16(a_, f2, acc[m][2], 0, 0, 0);
            acc[m][3] = __builtin_amdgcn_mfma_f32_16x16x32_bf16(a_, f3, acc[m][3], 0, 0, 0);
        }
        __builtin_amdgcn_sched_barrier(0);

        // drain ONLY the 9 W DMAs (next chunk reads that LDS buffer);
        // the 32 X loads stay in flight. Wave-private: no s_barrier needed.
        if (more) asm volatile("s_waitcnt vmcnt(32)" ::: "memory");
        __builtin_amdgcn_sched_barrier(0);
    }

#undef CVT
#undef WDMA
#undef XLOAD

    // ---- epilogue: in-register DFL decode + store ----
    // D layout (m89): value[r] = D[mtile*16 + q4*4 + r][col]
    float4 bcv[5];
#pragma unroll
    for (int m = 0; m < 5; ++m)
        bcv[m] = *(const float4*)(bcls + m * 16 + q4 * 4);

    const float LOG2E = 1.44269504088896f;

#pragma unroll
    for (int nf = 0; nf < 4; ++nf) {
        const int alocal = nf * 16 + col;
        const bool valid = alocal < nv;
        const int hw = hw0 + alocal;

        float dist[4];
#pragma unroll
        for (int g = 0; g < 4; ++g) {
            const float4 bbv = *(const float4*)(bbox + g * 16 + q4 * 4);
            const float v0 = acc[g][nf][0] + bbv.x;
            const float v1 = acc[g][nf][1] + bbv.y;
            const float v2 = acc[g][nf][2] + bbv.z;
            const float v3 = acc[g][nf][3] + bbv.w;
            // softmax over 16 bins: 4 regs x 4 lanes (col, col+16, col+32, col+48)
            float mx = fmaxf(fmaxf(v0, v1), fmaxf(v2, v3));
            mx = fmaxf(mx, __shfl_xor(mx, 16));
            mx = fmaxf(mx, __shfl_xor(mx, 32));
            const float e0 = __builtin_amdgcn_exp2f((v0 - mx) * LOG2E);
            const float e1 = __builtin_amdgcn_exp2f((v1 - mx) * LOG2E);
            const float e2 = __builtin_amdgcn_exp2f((v2 - mx) * LOG2E);
            const float e3 = __builtin_amdgcn_exp2f((v3 - mx) * LOG2E);
            float s  = e0 + e1 + e2 + e3;
            float ws = e1 + 2.f * e2 + 3.f * e3 + (float)(q4 * 4) * s;
            s  += __shfl_xor(s, 16);
            s  += __shfl_xor(s, 32);
            ws += __shfl_xor(ws, 16);
            ws += __shfl_xor(ws, 32);
            dist[g] = ws / s;
        }

        if (valid) {
            const size_t obase = ((size_t)b * 8400 + AOFF + hw) * 84;
            if (q4 == 0) {
                const float ax = (float)(hw % GW) + 0.5f;
                const float ay = (float)(hw / GW) + 0.5f;
                f32x4 bx;
                bx[0] = (ax + 0.5f * (dist[2] - dist[0])) * STRIDE;
                bx[1] = (ay + 0.5f * (dist[3] - dist[1])) * STRIDE;
                bx[2] = (dist[0] + dist[2]) * STRIDE;
                bx[3] = (dist[1] + dist[3]) * STRIDE;
                *(f32x4*)(out + obase) = bx;
            }
#pragma unroll
            for (int m = 0; m < 5; ++m) {
                f32x4 v;
                v[0] = acc[m + 4][nf][0] + bcv[m].x;
                v[1] = acc[m + 4][nf][1] + bcv[m].y;
                v[2] = acc[m + 4][nf][2] + bcv[m].z;
                v[3] = acc[m + 4][nf][3] + bcv[m].w;
                *(f32x4*)(out + obase + 4 + m * 16 + q4 * 4) = v;
            }
        }
    }
}

__global__ __launch_bounds__(64, 2)
void UltralyticsDetect_kernel(
        const float* __restrict__ x0, const float* __restrict__ x1, const float* __restrict__ x2,
        const unsigned char* __restrict__ wimg,
        const float* __restrict__ bb0, const float* __restrict__ bc0,
        const float* __restrict__ bb1, const float* __restrict__ bc1,
        const float* __restrict__ bb2, const float* __restrict__ bc2,
        float* __restrict__ out) {

    __shared__ __align__(16) unsigned char s_w[2 * WCHUNK];  // 18 KiB, wave-private

    const int bid = blockIdx.x;
    // Long (K=512) levels first so the tail is filled by short level-0 blocks:
    // level 1: 16 b * 25 tiles = 400 ; level 2: 16*7 = 112 ; level 0: 16*100 = 1600
    if (bid < 400) {
        run_level<1>(bid, x1, wimg, bb1, bc1, out, s_w);
    } else if (bid < 512) {
        run_level<2>(bid - 400, x2, wimg, bb2, bc2, out, s_w);
    } else {
        run_level<0>(bid - 512, x0, wimg, bb0, bc0, out, s_w);
    }
}

extern "C" void kernel_launch(void* const* d_in, const int* in_sizes, int n_in,
                              void* d_out, int out_size, void* d_ws, size_t ws_size,
                              hipStream_t stream) {
    const float* x0  = (const float*)d_in[0];
    const float* x1  = (const float*)d_in[1];
    const float* x2  = (const float*)d_in[2];
    const float* wb0 = (const float*)d_in[3];
    const float* bb0 = (const float*)d_in[4];
    const float* wc0 = (const float*)d_in[5];
    const float* bc0 = (const float*)d_in[6];
    const float* wb1 = (const float*)d_in[7];
    const float* bb1 = (const float*)d_in[8];
    const float* wc1 = (const float*)d_in[9];
    const float* bc1 = (const float*)d_in[10];
    const float* wb2 = (const float*)d_in[11];
    const float* bb2 = (const float*)d_in[12];
    const float* wc2 = (const float*)d_in[13];
    const float* bc2 = (const float*)d_in[14];

    unsigned char* wimg = (unsigned char*)d_ws;

    prep_w_kernel<<<90, 256, 0, stream>>>(wb0, wc0, wb1, wc1, wb2, wc2, wimg);

    UltralyticsDetect_kernel<<<2112, 64, 0, stream>>>(
        x0, x1, x2, wimg,
        bb0, bc0, bb1, bc1, bb2, bc2,
        (float*)d_out);
}

// Round 9
// 48.326 us; speedup vs baseline: 1.0577x; 1.0337x over previous
//
#include <hip/hip_runtime.h>

// UltralyticsDetect head, fused: per-level 1x1-conv GEMM (M=144, K=C, N=B*HW)
// in bf16 MFMA + in-register DFL softmax decode + output assembly.
// Output: (16, 8400, 84) f32.
//
// R9: kill the thin X gather (was 137 thin VMEM instr/chunk-block across
// R6-R8, all ~50us). X is staged f32 via async global_load_lds dwordx4
// (25 wide VMEM instr/chunk-block) into LDS [32k][128anchor] with both-sides
// swizzle (pre-permuted per-lane SOURCE + XOR'd read addr, m173/m104).
// 256-thread blocks / 128 anchors / 3 blocks/CU. Tail tiles window-shift
// (hw0=min(hw0,HW-128)); overlapped blocks write identical values.

typedef __bf16 bf16x8 __attribute__((ext_vector_type(8)));
typedef float  f32x4  __attribute__((ext_vector_type(4)));

#define NTHREADS 256

// W image in d_ws: per level, C/32 chunks of 144 rows * 64 B, pre-swizzled.
#define WCHUNK 9216              // 144 * 64 B
#define WOFF0 0
#define WOFF1 73728              // level0: 8 chunks
#define WOFF2 221184             // level1: 16 chunks ; level2: 16 chunks after

#define XBUF 16384               // 32 rows * 512 B (128 anchors f32)

// round-half-up f32 -> bf16, pack two into one u32 (a -> low16, b -> high16)
__device__ __forceinline__ unsigned int pack_bf16(float a, float b) {
    unsigned int ua = __builtin_bit_cast(unsigned int, a);
    unsigned int ub = __builtin_bit_cast(unsigned int, b);
    return ((ua + 0x8000u) >> 16) | ((ub + 0x8000u) & 0xffff0000u);
}

// W LDS tile: [144 rows][32 bf16] = 64B rows, 16B-slot swizzle.
__device__ __forceinline__ int swz32(int row, int kbyte) {
    return row * 64 + (kbyte ^ ((((row & 3) ^ ((row >> 2) & 1))) << 4));
}

// async global->LDS, 16B per lane
__device__ __forceinline__ void gload_lds16(const void* g, void* l) {
    __builtin_amdgcn_global_load_lds(
        (const __attribute__((address_space(1))) void*)g,
        (__attribute__((address_space(3))) void*)l, 16, 0, 0);
}

// ---------------- prep kernel: W f32 -> bf16, pre-swizzled into d_ws --------
__global__ __launch_bounds__(256)
void prep_w_kernel(const float* __restrict__ wb0, const float* __restrict__ wc0,
                   const float* __restrict__ wb1, const float* __restrict__ wc1,
                   const float* __restrict__ wb2, const float* __restrict__ wc2,
                   unsigned char* __restrict__ ws) {
    int uid = blockIdx.x * 256 + threadIdx.x;   // one unit = 8 k-elems
    if (uid >= 23040) return;                   // 4608 + 9216 + 9216
    const float* wb; const float* wc; int C; size_t off; int uu;
    if (uid < 4608)       { wb = wb0; wc = wc0; C = 256; off = WOFF0; uu = uid; }
    else if (uid < 13824) { wb = wb1; wc = wc1; C = 512; off = WOFF1; uu = uid - 4608; }
    else                  { wb = wb2; wc = wc2; C = 512; off = WOFF2; uu = uid - 13824; }
    const int kunits = C / 8;
    const int row = uu / kunits;
    const int k   = (uu % kunits) * 8;
    const float* src = ((row < 64) ? (wb + row * C) : (wc + (row - 64) * C)) + k;
    const float4 f0 = *(const float4*)(src);
    const float4 f1 = *(const float4*)(src + 4);
    uint4 p;
    p.x = pack_bf16(f0.x, f0.y);
    p.y = pack_bf16(f0.z, f0.w);
    p.z = pack_bf16(f1.x, f1.y);
    p.w = pack_bf16(f1.z, f1.w);
    const int chunk = k >> 5;            // 32-k chunks
    const int kg    = (k & 31) >> 3;     // 16B slot within row
    *(uint4*)(ws + off + (size_t)chunk * WCHUNK + swz32(row, kg * 16)) = p;
}

// ---------------- main kernel ----------------------------------------------
template <int LVL>
__device__ __forceinline__ void run_level(
        int rb,
        const float* __restrict__ x,
        const unsigned char* __restrict__ wimg_all,
        const float* __restrict__ bbox, const float* __restrict__ bcls,
        float* __restrict__ out,
        unsigned char* s_w, unsigned char* s_x) {

    constexpr int    C      = (LVL == 0) ? 256 : 512;
    constexpr int    GW     = (LVL == 0) ? 80 : (LVL == 1 ? 40 : 20);
    constexpr int    HW     = GW * GW;
    constexpr int    AOFF   = (LVL == 0) ? 0 : (LVL == 1 ? 6400 : 8000);
    constexpr float  STRIDE = (LVL == 0) ? 8.0f : (LVL == 1 ? 16.0f : 32.0f);
    constexpr int    TPB    = (HW + 127) / 128;  // 128-anchor tiles per image
    constexpr size_t WOFF   = (LVL == 0) ? WOFF0 : (LVL == 1 ? WOFF1 : WOFF2);
    const int nkc = C / 32;

    const int b    = rb / TPB;
    const int tile = rb % TPB;
    int hw0 = tile * 128;
    if (hw0 > HW - 128) hw0 = HW - 128;   // tail tiles overlap previous tile

    const int tid  = threadIdx.x;
    const int wv   = tid >> 6;        // wave 0..3
    const int lane = tid & 63;
    const int col  = lane & 15;       // MFMA n/col lane
    const int q4   = lane >> 4;       // MFMA row-quarter

    const float* xlev = x + (size_t)b * C * HW;
    const unsigned char* wimg = wimg_all + WOFF;

    // X DMA: wave wv stages rows wv*8..wv*8+7 (4 instr x 2 rows). Source
    // anchor-group pre-permuted by wv so swizzled reads see linear data.
    const int xg  = (((lane & 31) ^ (wv << 2)) << 2);  // anchor offset (4/grp)
    const int xr  = lane >> 5;                          // row parity
    // X frag read bases: byte = r*512 + ((a<<2) ^ (q4<<6)), a = wv*32+f*16+col
    const int xrd0 = (((wv * 32 + col) << 2) ^ (q4 << 6)) + q4 * 8 * 512;
    const int xrd1 = (((wv * 32 + 16 + col) << 2) ^ (q4 << 6)) + q4 * 8 * 512;

    f32x4 acc[9][2];
#pragma unroll
    for (int m = 0; m < 9; ++m) {
        acc[m][0] = (f32x4){0.f, 0.f, 0.f, 0.f};
        acc[m][1] = (f32x4){0.f, 0.f, 0.f, 0.f};
    }

#define XDMA(CC, BUF)                                                       \
    {                                                                       \
        _Pragma("unroll")                                                   \
        for (int _i = 0; _i < 4; ++_i) {                                    \
            const int _r2 = wv * 8 + _i * 2;                                \
            gload_lds16(xlev + (size_t)((CC) * 32 + _r2 + xr) * HW + hw0 + xg, \
                        s_x + (BUF) * XBUF + _r2 * 512);                    \
        }                                                                   \
    }

#define WDMA(CC, BUF)                                                       \
    {                                                                       \
        _Pragma("unroll")                                                   \
        for (int _i = 0; _i < 3; ++_i) {                                    \
            const int _u = tid + _i * 256;                                  \
            if (_u < 576)                                                   \
                gload_lds16(wimg + (size_t)(CC) * WCHUNK + _u * 16,         \
                            s_w + (BUF) * WCHUNK + _u * 16);                \
        }                                                                   \
    }

    // ---- prologue: stage chunk 0 ----
    XDMA(0, 0);
    WDMA(0, 0);
    __builtin_amdgcn_sched_barrier(0);
    asm volatile("s_waitcnt vmcnt(0)" ::: "memory");
    __builtin_amdgcn_s_barrier();
    __builtin_amdgcn_sched_barrier(0);

    for (int kc = 0; kc < nkc; ++kc) {
        const int cur = kc & 1;
        const bool more = (kc + 1 < nkc);

        if (more) {                      // issue next chunk's DMAs first
            XDMA(kc + 1, cur ^ 1);
            WDMA(kc + 1, cur ^ 1);
        }
        __builtin_amdgcn_sched_barrier(0);

        // ---- X fragments from LDS (swizzled, 2-way-free) + convert ----
        const unsigned char* xbuf = s_x + cur * XBUF;
        float xf0[8], xf1[8];
#pragma unroll
        for (int j = 0; j < 8; ++j) {
            xf0[j] = *(const float*)(xbuf + xrd0 + j * 512);
            xf1[j] = *(const float*)(xbuf + xrd1 + j * 512);
        }
        uint4 qa, qb;
        qa.x = pack_bf16(xf0[0], xf0[1]); qa.y = pack_bf16(xf0[2], xf0[3]);
        qa.z = pack_bf16(xf0[4], xf0[5]); qa.w = pack_bf16(xf0[6], xf0[7]);
        qb.x = pack_bf16(xf1[0], xf1[1]); qb.y = pack_bf16(xf1[2], xf1[3]);
        qb.z = pack_bf16(xf1[4], xf1[5]); qb.w = pack_bf16(xf1[6], xf1[7]);
        const bf16x8 fA = __builtin_bit_cast(bf16x8, qa);
        const bf16x8 fB = __builtin_bit_cast(bf16x8, qb);

        // ---- MFMA: 9 M-tiles x 2 N-frags; one A-read feeds 2 MFMAs ----
        const unsigned char* wbuf = s_w + cur * WCHUNK;
#pragma unroll
        for (int m = 0; m < 9; ++m) {
            const bf16x8 a_ = *(const bf16x8*)(wbuf + swz32(m * 16 + col, q4 * 16));
            acc[m][0] = __builtin_amdgcn_mfma_f32_16x16x32_bf16(a_, fA, acc[m][0], 0, 0, 0);
            acc[m][1] = __builtin_amdgcn_mfma_f32_16x16x32_bf16(a_, fB, acc[m][1], 0, 0, 0);
        }
        __builtin_amdgcn_sched_barrier(0);

        if (more) {
            asm volatile("s_waitcnt vmcnt(0)" ::: "memory");  // own 7 DMAs done
            __builtin_amdgcn_s_barrier();
            __builtin_amdgcn_sched_barrier(0);
        }
    }

#undef WDMA
#undef XDMA

    // ---- epilogue: in-register DFL decode + store ----
    // D layout (m89): value[r] = D[mtile*16 + q4*4 + r][col]
    float4 bcv[5];
#pragma unroll
    for (int m = 0; m < 5; ++m)
        bcv[m] = *(const float4*)(bcls + m * 16 + q4 * 4);

    const float LOG2E = 1.44269504088896f;

#pragma unroll
    for (int nf = 0; nf < 2; ++nf) {
        const int alocal = wv * 32 + nf * 16 + col;
        const int hw = hw0 + alocal;

        float dist[4];
#pragma unroll
        for (int g = 0; g < 4; ++g) {
            const float4 bbv = *(const float4*)(bbox + g * 16 + q4 * 4);
            const float v0 = acc[g][nf][0] + bbv.x;
            const float v1 = acc[g][nf][1] + bbv.y;
            const float v2 = acc[g][nf][2] + bbv.z;
            const float v3 = acc[g][nf][3] + bbv.w;
            // softmax over 16 bins: 4 regs x 4 lanes (col, col+16, col+32, col+48)
            float mx = fmaxf(fmaxf(v0, v1), fmaxf(v2, v3));
            mx = fmaxf(mx, __shfl_xor(mx, 16));
            mx = fmaxf(mx, __shfl_xor(mx, 32));
            const float e0 = __builtin_amdgcn_exp2f((v0 - mx) * LOG2E);
            const float e1 = __builtin_amdgcn_exp2f((v1 - mx) * LOG2E);
            const float e2 = __builtin_amdgcn_exp2f((v2 - mx) * LOG2E);
            const float e3 = __builtin_amdgcn_exp2f((v3 - mx) * LOG2E);
            float s  = e0 + e1 + e2 + e3;
            float ws = e1 + 2.f * e2 + 3.f * e3 + (float)(q4 * 4) * s;
            s  += __shfl_xor(s, 16);
            s  += __shfl_xor(s, 32);
            ws += __shfl_xor(ws, 16);
            ws += __shfl_xor(ws, 32);
            dist[g] = ws / s;
        }

        const size_t obase = ((size_t)b * 8400 + AOFF + hw) * 84;
        if (q4 == 0) {
            const float ax = (float)(hw % GW) + 0.5f;
            const float ay = (float)(hw / GW) + 0.5f;
            f32x4 bx;
            bx[0] = (ax + 0.5f * (dist[2] - dist[0])) * STRIDE;
            bx[1] = (ay + 0.5f * (dist[3] - dist[1])) * STRIDE;
            bx[2] = (dist[0] + dist[2]) * STRIDE;
            bx[3] = (dist[1] + dist[3]) * STRIDE;
            *(f32x4*)(out + obase) = bx;
        }
#pragma unroll
        for (int m = 0; m < 5; ++m) {
            f32x4 v;
            v[0] = acc[m + 4][nf][0] + bcv[m].x;
            v[1] = acc[m + 4][nf][1] + bcv[m].y;
            v[2] = acc[m + 4][nf][2] + bcv[m].z;
            v[3] = acc[m + 4][nf][3] + bcv[m].w;
            *(f32x4*)(out + obase + 4 + m * 16 + q4 * 4) = v;
        }
    }
}

__global__ __launch_bounds__(NTHREADS, 3)
void UltralyticsDetect_kernel(
        const float* __restrict__ x0, const float* __restrict__ x1, const float* __restrict__ x2,
        const unsigned char* __restrict__ wimg,
        const float* __restrict__ bb0, const float* __restrict__ bc0,
        const float* __restrict__ bb1, const float* __restrict__ bc1,
        const float* __restrict__ bb2, const float* __restrict__ bc2,
        float* __restrict__ out) {

    __shared__ __align__(16) unsigned char s_w[2 * WCHUNK];  // 18 KiB dbuf
    __shared__ __align__(16) unsigned char s_x[2 * XBUF];    // 32 KiB dbuf

    const int bid = blockIdx.x;
    // Long (K=512) levels first so the tail is filled by short level-0 blocks:
    // level 1: 16 b * 13 tiles = 208 ; level 2: 16*4 = 64 ; level 0: 16*50 = 800
    if (bid < 208) {
        run_level<1>(bid, x1, wimg, bb1, bc1, out, s_w, s_x);
    } else if (bid < 272) {
        run_level<2>(bid - 208, x2, wimg, bb2, bc2, out, s_w, s_x);
    } else {
        run_level<0>(bid - 272, x0, wimg, bb0, bc0, out, s_w, s_x);
    }
}

extern "C" void kernel_launch(void* const* d_in, const int* in_sizes, int n_in,
                              void* d_out, int out_size, void* d_ws, size_t ws_size,
                              hipStream_t stream) {
    const float* x0  = (const float*)d_in[0];
    const float* x1  = (const float*)d_in[1];
    const float* x2  = (const float*)d_in[2];
    const float* wb0 = (const float*)d_in[3];
    const float* bb0 = (const float*)d_in[4];
    const float* wc0 = (const float*)d_in[5];
    const float* bc0 = (const float*)d_in[6];
    const float* wb1 = (const float*)d_in[7];
    const float* bb1 = (const float*)d_in[8];
    const float* wc1 = (const float*)d_in[9];
    const float* bc1 = (const float*)d_in[10];
    const float* wb2 = (const float*)d_in[11];
    const float* bb2 = (const float*)d_in[12];
    const float* wc2 = (const float*)d_in[13];
    const float* bc2 = (const float*)d_in[14];

    unsigned char* wimg = (unsigned char*)d_ws;

    prep_w_kernel<<<90, 256, 0, stream>>>(wb0, wc0, wb1, wc1, wb2, wc2, wimg);

    UltralyticsDetect_kernel<<<1072, NTHREADS, 0, stream>>>(
        x0, x1, x2, wimg,
        bb0, bc0, bb1, bc1, bb2, bc2,
        (float*)d_out);
}